// Round 1
// baseline (5557.740 us; speedup 1.0000x reference)
//
#include <hip/hip_runtime.h>
#include <stdint.h>

typedef __bf16 bf16;
typedef __attribute__((ext_vector_type(8))) __bf16 bf16x8;
typedef __attribute__((ext_vector_type(4))) float floatx4;

#define NTOK   1024     // tokens per batch (N)
#define TOKS   8192     // B*N
#define HID_   1024
#define FFN_   2730
#define FFNP   2816     // FFN padded to mult of 128 (even count of 64-wide K tiles)
#define X12N   5460     // 2*FFN

#define EPI_BF16  0
#define EPI_QKV   1
#define EPI_RESID 2

// ---------------------------------------------------------------- fp32 -> bf16 weight conversion
__global__ __launch_bounds__(256) void conv_bf16(const float* __restrict__ in, bf16* __restrict__ out, int n)
{
    const int i = (blockIdx.x * 256 + threadIdx.x) * 4;
    if (i >= n) return;
    const float4 v = *(const float4*)(in + i);
    out[i + 0] = (bf16)v.x; out[i + 1] = (bf16)v.y;
    out[i + 2] = (bf16)v.z; out[i + 3] = (bf16)v.w;
}

// w3 (1024 x 2730) fp32 -> (1024 x 2816) bf16 zero-padded
__global__ void conv_pad_w3(const float* __restrict__ w3, bf16* __restrict__ w3p)
{
    const int kk = blockIdx.x * 256 + threadIdx.x;
    const int row = blockIdx.y;
    if (kk >= FFNP) return;
    w3p[(size_t)row * FFNP + kk] = (kk < FFN_) ? (bf16)w3[(size_t)row * FFN_ + kk] : (bf16)0.f;
}

// ---------------------------------------------------------------- GEMM: 256x256 tile, 8-phase pipeline
// C[M x Nreal] = A[M x K] * Bm[Nreal x K]^T (+bias). 512 thr = 8 waves (2x4).
// BK=64, double-buffered 128KiB LDS, counted vmcnt (never 0 in steady state),
// chunk-swizzled LDS (inverse-swizzled global source + swizzled ds_read),
// setprio around MFMA cluster, bijective XCD block swizzle.
#define GLL(src, dst) __builtin_amdgcn_global_load_lds( \
    (const __attribute__((address_space(1))) void*)(src), \
    (__attribute__((address_space(3))) void*)(dst), 16, 0, 0)

#define STAGE_A(bufi, hi, tile) GLL(pA[hi] + (size_t)(tile) * 64, As + (bufi) * 16384 + ((hi) * 512 + t) * 8)
#define STAGE_B(bufi, hi, tile) GLL(pB[hi] + (size_t)(tile) * 64, Bs + (bufi) * 16384 + ((hi) * 512 + t) * 8)

#define LOADA(bufi, qm) { _Pragma("unroll") for (int mf = 0; mf < 4; mf++) { \
    a[mf][0] = *(const bf16x8*)(As + (bufi) * 16384 + (qm) * 8192 + arow64 + mf * 1024 + swz0); \
    a[mf][1] = *(const bf16x8*)(As + (bufi) * 16384 + (qm) * 8192 + arow64 + mf * 1024 + swz1); } }

#define LOADB(bufi, qn) { _Pragma("unroll") for (int nf = 0; nf < 2; nf++) { \
    b[nf][0] = *(const bf16x8*)(Bs + (bufi) * 16384 + (qn) * 8192 + brow64 + nf * 1024 + swz0); \
    b[nf][1] = *(const bf16x8*)(Bs + (bufi) * 16384 + (qn) * 8192 + brow64 + nf * 1024 + swz1); } }

#define MM(qm, qn) { _Pragma("unroll") for (int mf = 0; mf < 4; mf++) \
    _Pragma("unroll") for (int nf = 0; nf < 2; nf++) { \
    acc[qm][qn][mf][nf] = __builtin_amdgcn_mfma_f32_16x16x32_bf16(a[mf][0], b[nf][0], acc[qm][qn][mf][nf], 0, 0, 0); \
    acc[qm][qn][mf][nf] = __builtin_amdgcn_mfma_f32_16x16x32_bf16(a[mf][1], b[nf][1], acc[qm][qn][mf][nf], 0, 0, 0); } }

#define PHTAIL(...) { __builtin_amdgcn_s_barrier(); \
    asm volatile("s_waitcnt lgkmcnt(0)" ::: "memory"); \
    __builtin_amdgcn_sched_barrier(0); \
    __builtin_amdgcn_s_setprio(1); __VA_ARGS__; __builtin_amdgcn_s_setprio(0); \
    __builtin_amdgcn_s_barrier(); }

__global__ __launch_bounds__(512, 2) void gemm256(
    const bf16* __restrict__ A, const bf16* __restrict__ Bm, const float* __restrict__ bias,
    int K, int Nreal, int epi,
    bf16* __restrict__ outb, int ldo,
    bf16* __restrict__ qo, bf16* __restrict__ ko, bf16* __restrict__ vo,
    float* __restrict__ hres, const float* __restrict__ gate, int gstride)
{
    __shared__ __align__(16) bf16 As[2 * 16384];   // [buf][256 rows][64 k], chunk-swizzled
    __shared__ __align__(16) bf16 Bs[2 * 16384];
    const int t = threadIdx.x;

    // bijective XCD-aware block swizzle (m204)
    const int gx = gridDim.x;
    int wg = blockIdx.y * gx + blockIdx.x;
    {
        const int nwg = gx * gridDim.y;
        const int q8 = nwg >> 3, r8 = nwg & 7;
        const int xcd = wg & 7, pos = wg >> 3;
        wg = (xcd < r8 ? xcd * (q8 + 1) : r8 * (q8 + 1) + (xcd - r8) * q8) + pos;
    }
    const int M0 = (wg / gx) * 256, N0 = (wg % gx) * 256;
    const int Nlast = Nreal - 1;

    const int lane = t & 63, w = t >> 6;
    const int wm = w >> 2, wn = w & 3;            // 2 x 4 wave grid
    const int quad = lane >> 4, r16 = lane & 15;

    // staging: thread t stages 16B chunk; dest LDS slot linear, source chunk inverse-swizzled
    const int rS = t >> 3;                        // dest row within 64-row group
    const int cswS = (t & 7) ^ (rS & 7);          // source chunk for this dest slot
    const bf16* pA[4]; const bf16* pB[4];
    #pragma unroll
    for (int hi = 0; hi < 4; hi++) {
        pA[hi] = A + (size_t)(M0 + hi * 64 + rS) * K + cswS * 8;
        int nb = N0 + hi * 64 + rS; if (nb > Nlast) nb = Nlast;
        pB[hi] = Bm + (size_t)nb * K + cswS * 8;
    }

    // ds_read bases (elements); swizzled chunk offsets per k-step
    const int arow64 = (wm * 64 + r16) * 64;
    const int brow64 = (wn * 32 + r16) * 64;
    const int swz0 = ((0 * 4 + quad) ^ (r16 & 7)) * 8;
    const int swz1 = ((1 * 4 + quad) ^ (r16 & 7)) * 8;

    floatx4 acc[2][2][4][2];
    const floatx4 zero = {0.f, 0.f, 0.f, 0.f};
    #pragma unroll
    for (int i0 = 0; i0 < 2; i0++)
        #pragma unroll
        for (int i1 = 0; i1 < 2; i1++)
            #pragma unroll
            for (int i2 = 0; i2 < 4; i2++)
                #pragma unroll
                for (int i3 = 0; i3 < 2; i3++) acc[i0][i1][i2][i3] = zero;
    bf16x8 a[4][2], b[2][2];

    const int NT = K >> 6;       // 64-wide K tiles (even by construction)
    const int NI = NT >> 1;

    // ---- prologue: tile0 full + bottom(A0,B0) of tile1; FIFO order matters for vmcnt math
    STAGE_A(0, 0, 0); STAGE_A(0, 1, 0);
    STAGE_B(0, 0, 0); STAGE_B(0, 1, 0);
    STAGE_B(0, 2, 0); STAGE_B(0, 3, 0);
    STAGE_A(0, 2, 0); STAGE_A(0, 3, 0);
    STAGE_A(1, 0, 1); STAGE_A(1, 1, 1);
    STAGE_B(1, 0, 1); STAGE_B(1, 1, 1);
    asm volatile("s_waitcnt vmcnt(4)" ::: "memory");   // tile0 fully landed; tile1 A0/B0 in flight
    __builtin_amdgcn_s_barrier();

    for (int it = 0; it < NI; ++it) {
        const bool last = (it == NI - 1);
        const int to = 2 * it + 1, te2 = 2 * it + 2, to2 = 2 * it + 3;
        // ---- even tile (buf0): quadrants (qm,qn)
        // P1
        LOADA(0, 0); LOADB(0, 0);
        STAGE_A(1, 2, to); STAGE_A(1, 3, to);
        PHTAIL(MM(0, 0));
        // P2
        LOADB(0, 1);
        STAGE_B(1, 2, to); STAGE_B(1, 3, to);
        PHTAIL(MM(0, 1));
        // P3
        LOADA(0, 1); LOADB(0, 0);
        if (!last) { STAGE_A(0, 0, te2); STAGE_A(0, 1, te2); }
        PHTAIL(MM(1, 0));
        // P4 (vmcnt point)
        LOADB(0, 1);
        if (!last) { STAGE_B(0, 0, te2); STAGE_B(0, 1, te2);
                     asm volatile("s_waitcnt vmcnt(4)" ::: "memory"); }
        else       { asm volatile("s_waitcnt vmcnt(0)" ::: "memory"); }
        PHTAIL(MM(1, 1));
        // ---- odd tile (buf1)
        // P5
        LOADA(1, 0); LOADB(1, 0);
        if (!last) { STAGE_A(0, 2, te2); STAGE_A(0, 3, te2); }
        PHTAIL(MM(0, 0));
        // P6
        LOADB(1, 1);
        if (!last) { STAGE_B(0, 2, te2); STAGE_B(0, 3, te2); }
        PHTAIL(MM(0, 1));
        // P7
        LOADA(1, 1); LOADB(1, 0);
        if (!last) { STAGE_A(1, 0, to2); STAGE_A(1, 1, to2); }
        PHTAIL(MM(1, 0));
        // P8 (vmcnt point)
        LOADB(1, 1);
        if (!last) { STAGE_B(1, 0, to2); STAGE_B(1, 1, to2);
                     asm volatile("s_waitcnt vmcnt(4)" ::: "memory"); }
        PHTAIL(MM(1, 1));
    }

    // ---- epilogue: row = M0+qm*128+wm*64+mf*16+quad*4+rr, col = N0+qn*128+wn*32+nf*16+r16
    #pragma unroll
    for (int qm = 0; qm < 2; qm++)
    #pragma unroll
    for (int mf = 0; mf < 4; mf++) {
        const int rbase = M0 + qm * 128 + wm * 64 + mf * 16 + quad * 4;
        #pragma unroll
        for (int qn = 0; qn < 2; qn++)
        #pragma unroll
        for (int nf = 0; nf < 2; nf++) {
            const int col = N0 + qn * 128 + wn * 32 + nf * 16 + r16;
            if (col >= Nreal) continue;
            const float bv = bias[col];
            const floatx4 av = acc[qm][qn][mf][nf];
            if (epi == EPI_BF16) {
                #pragma unroll
                for (int rr = 0; rr < 4; rr++)
                    outb[(size_t)(rbase + rr) * ldo + col] = (bf16)(av[rr] + bv);
            } else if (epi == EPI_QKV) {
                const int s = col >> 10, hh = (col >> 6) & 15, dd = col & 63;
                #pragma unroll
                for (int rr = 0; rr < 4; rr++) {
                    const int row = rbase + rr;
                    const int bb = row >> 10, n = row & 1023;
                    const float vv = av[rr] + bv;
                    if (s == 0)      qo[((size_t)(bb * 16 + hh) * 1024 + n) * 64 + dd] = (bf16)vv;
                    else if (s == 1) ko[((size_t)(bb * 16 + hh) * 1024 + n) * 64 + dd] = (bf16)vv;
                    else             vo[((size_t)(bb * 16 + hh) * 64 + dd) * 1024 + n] = (bf16)vv;  // V^T
                }
            } else { // EPI_RESID: h += gate * (acc + bias)
                #pragma unroll
                for (int rr = 0; rr < 4; rr++) {
                    const int row = rbase + rr;
                    const int bb = row >> 10;
                    hres[(size_t)row * 1024 + col] += gate[(size_t)bb * gstride + col] * (av[rr] + bv);
                }
            }
        }
    }
}

// ---------------------------------------------------------------- small GEMM (8 x N) = A(8 x K) * W(N x K)^T
__global__ __launch_bounds__(256) void small_gemm(
    const float* __restrict__ Aws, const float* __restrict__ t_in,
    const float* __restrict__ W, const float* __restrict__ bias,
    float* __restrict__ out, int N, int K, int mode, int dosilu)
{
    const int w = threadIdx.x >> 6, lane = threadIdx.x & 63;
    const int col = blockIdx.x * 4 + w;
    float acc[8];
    #pragma unroll
    for (int bb = 0; bb < 8; bb++) acc[bb] = 0.f;
    float tb[8];
    if (mode == 1) {
        #pragma unroll
        for (int bb = 0; bb < 8; bb++) tb[bb] = t_in[bb];
    }
    for (int kk = lane; kk < K; kk += 64) {
        const float wv = W[(size_t)col * K + kk];
        if (mode == 1) {
            const float f = __expf(-(float)(kk & 127) * (9.21034037198f / 128.f));
            #pragma unroll
            for (int bb = 0; bb < 8; bb++) {
                const float arg = tb[bb] * f;
                const float e = (kk < 128) ? cosf(arg) : sinf(arg);
                acc[bb] += e * wv;
            }
        } else {
            #pragma unroll
            for (int bb = 0; bb < 8; bb++) acc[bb] += Aws[(size_t)bb * 1024 + kk] * wv;
        }
    }
    #pragma unroll
    for (int bb = 0; bb < 8; bb++) {
        float v2 = acc[bb];
        #pragma unroll
        for (int off = 32; off; off >>= 1) v2 += __shfl_xor(v2, off, 64);
        acc[bb] = v2;
    }
    if (lane == 0) {
        const float bv = bias[col];
        #pragma unroll
        for (int bb = 0; bb < 8; bb++) {
            float vv = acc[bb] + bv;
            if (dosilu) vv = vv / (1.f + __expf(-vv));
            out[(size_t)bb * N + col] = vv;
        }
    }
}

// ---------------------------------------------------------------- patch embed + pos embed -> h (fp32)
__global__ __launch_bounds__(256) void patch_embed(
    const float* __restrict__ x, const float* __restrict__ pw, const float* __restrict__ pb,
    float* __restrict__ h)
{
    __shared__ float xs[32];
    const int row = blockIdx.x, t = threadIdx.x;
    const int b = row >> 10, n = row & 1023;
    const int hp = n >> 4, wp = n & 15;
    if (t < 32) {
        const int c = t >> 4, ph = (t >> 2) & 3, pq = t & 3;
        xs[t] = x[((size_t)(b * 2 + c) * 256 + hp * 4 + ph) * 64 + wp * 4 + pq];
    }
    __syncthreads();
    #pragma unroll
    for (int rep = 0; rep < 4; rep++) {
        const int o = t + rep * 256;
        const float* wrow = pw + (size_t)o * 32;
        float acc = pb[o];
        #pragma unroll
        for (int e = 0; e < 32; e++) acc += xs[e] * wrow[e];
        const int seg = o >> 8, oo = o & 255;
        const float om = __expf(-(float)oo * (9.21034037198f / 256.f));
        const float pos = (seg < 2) ? (float)wp : (float)hp;
        const float arg = pos * om;
        const float pe = ((seg & 1) == 0) ? sinf(arg) : cosf(arg);
        h[(size_t)row * 1024 + o] = acc + pe;
    }
}

// ---------------------------------------------------------------- rmsnorm + modulate -> bf16
__global__ __launch_bounds__(256) void norm_mod(
    const float* __restrict__ h, const float* __restrict__ w,
    const float* __restrict__ ada, int sh_off, int sc_off, int stride,
    bf16* __restrict__ out)
{
    __shared__ float red[4];
    const int row = blockIdx.x, t = threadIdx.x;
    const int b = row >> 10;
    const float4 xv = ((const float4*)(h + (size_t)row * 1024))[t];
    float ss = xv.x * xv.x + xv.y * xv.y + xv.z * xv.z + xv.w * xv.w;
    #pragma unroll
    for (int off = 32; off; off >>= 1) ss += __shfl_xor(ss, off, 64);
    if ((t & 63) == 0) red[t >> 6] = ss;
    __syncthreads();
    const float total = red[0] + red[1] + red[2] + red[3];
    const float rms = rsqrtf(total * (1.f / 1024.f) + 1e-6f);
    const float* sh = ada + (size_t)b * stride + sh_off;
    const float* sc = ada + (size_t)b * stride + sc_off;
    const float vals[4] = {xv.x, xv.y, xv.z, xv.w};
    #pragma unroll
    for (int e = 0; e < 4; e++) {
        const int c2 = t * 4 + e;
        const float vv = vals[e] * rms * w[c2] * (1.f + sc[c2]) + sh[c2];
        out[(size_t)row * 1024 + c2] = (bf16)vv;
    }
}

// ---------------------------------------------------------------- qk rmsnorm + RoPE (in place), 4 rows/block
__global__ __launch_bounds__(256) void rope_qk(
    bf16* __restrict__ q, bf16* __restrict__ k,
    const float* __restrict__ qw, const float* __restrict__ kw)
{
    const int n = blockIdx.x * 4 + (threadIdx.x >> 6);
    const int bh = blockIdx.y, d = threadIdx.x & 63;
    const size_t idx = ((size_t)bh * 1024 + n) * 64 + d;
    const float qv = (float)q[idx], kv = (float)k[idx];
    float sq = qv * qv, sk = kv * kv;
    #pragma unroll
    for (int off = 32; off; off >>= 1) { sq += __shfl_xor(sq, off, 64); sk += __shfl_xor(sk, off, 64); }
    const float rq = rsqrtf(sq * (1.f / 64.f) + 1e-6f);
    const float rk = rsqrtf(sk * (1.f / 64.f) + 1e-6f);
    const float qn = qv * rq * qw[d];
    const float kn = kv * rk * kw[d];
    const int j = (d & 31) >> 1;
    const float freq = __expf(-(float)j * (9.21034037198f / 16.f));   // 10000^(-j/16)
    const float pos = (d < 32) ? (float)(n >> 4) : (float)(n & 15);
    const float ang = pos * freq;
    const float cv = cosf(ang), sv = sinf(ang);
    const float qp = __shfl_xor(qn, 1, 64);
    const float kp = __shfl_xor(kn, 1, 64);
    const float qo = qn * cv + ((d & 1) ? qp : -qp) * sv;
    const float ko = kn * cv + ((d & 1) ? kp : -kp) * sv;
    q[idx] = (bf16)qo;
    k[idx] = (bf16)ko;
}

// ---------------------------------------------------------------- MFMA flash attention
// grid (16 qtiles, 128 bh), 256 threads = 4 waves; wave wq owns q rows wq*16..+15.
// q,k: [bh][n][64] bf16.  v: PRE-TRANSPOSED [bh][64][n] bf16.  o: [b][n][h*64+d].
__global__ __launch_bounds__(256) void attn_kernel(
    const bf16* __restrict__ q, const bf16* __restrict__ k, const bf16* __restrict__ v,
    bf16* __restrict__ o)
{
    __shared__ __align__(16) bf16 Qs[2 * 64 * 32];   // [half_d][row q][32]
    __shared__ __align__(16) bf16 Ks[2 * 64 * 32];   // [half_d][row ktok][32]
    __shared__ __align__(16) bf16 Vt[2 * 64 * 32];   // [half_ktok][row d][32]
    __shared__ __align__(16) bf16 Pw[4 * 16 * 80];   // per-wave P, row stride 80
    const int t = threadIdx.x;
    const int l = t & 63, wq = t >> 6;
    const int quad = l >> 4, r16 = l & 15;
    const int qt = blockIdx.x, bh = blockIdx.y;
    const int b = bh >> 4, hh = bh & 15;

    #pragma unroll
    for (int m = 0; m < 2; m++) {
        const bf16* g = q + ((size_t)bh * 1024 + qt * 64 + wq * 16 + (l >> 2)) * 64 + m * 32 + (l & 3) * 8;
        __builtin_amdgcn_global_load_lds((const __attribute__((address_space(1))) void*)g,
            (__attribute__((address_space(3))) void*)(Qs + m * 2048 + wq * 16 * 32 + l * 8), 16, 0, 0);
    }
    __syncthreads();
    bf16x8 afq[2];
    #pragma unroll
    for (int h2 = 0; h2 < 2; h2++)
        afq[h2] = *(const bf16x8*)(Qs + h2 * 2048 + (wq * 16 + r16) * 32 + quad * 8);

    float m_r[4], l_r[4];
    floatx4 oacc[4];
    const floatx4 zero = {0.f, 0.f, 0.f, 0.f};
    #pragma unroll
    for (int rr = 0; rr < 4; rr++) { m_r[rr] = -1e30f; l_r[rr] = 0.f; }
    #pragma unroll
    for (int jd = 0; jd < 4; jd++) oacc[jd] = zero;

    bf16* Pme = Pw + wq * 16 * 80;

    for (int kt = 0; kt < 16; kt++) {
        __syncthreads();
        #pragma unroll
        for (int m = 0; m < 2; m++) {
            const bf16* gk = k + ((size_t)bh * 1024 + kt * 64 + wq * 16 + (l >> 2)) * 64 + m * 32 + (l & 3) * 8;
            __builtin_amdgcn_global_load_lds((const __attribute__((address_space(1))) void*)gk,
                (__attribute__((address_space(3))) void*)(Ks + m * 2048 + wq * 16 * 32 + l * 8), 16, 0, 0);
            const bf16* gv = v + ((size_t)bh * 64 + wq * 16 + (l >> 2)) * 1024 + kt * 64 + m * 32 + (l & 3) * 8;
            __builtin_amdgcn_global_load_lds((const __attribute__((address_space(1))) void*)gv,
                (__attribute__((address_space(3))) void*)(Vt + m * 2048 + wq * 16 * 32 + l * 8), 16, 0, 0);
        }
        __syncthreads();

        floatx4 s[4];
        #pragma unroll
        for (int j = 0; j < 4; j++) {
            bf16x8 b0 = *(const bf16x8*)(Ks + 0 * 2048 + (j * 16 + r16) * 32 + quad * 8);
            bf16x8 b1 = *(const bf16x8*)(Ks + 1 * 2048 + (j * 16 + r16) * 32 + quad * 8);
            s[j] = __builtin_amdgcn_mfma_f32_16x16x32_bf16(afq[0], b0, zero, 0, 0, 0);
            s[j] = __builtin_amdgcn_mfma_f32_16x16x32_bf16(afq[1], b1, s[j], 0, 0, 0);
        }
        float alpha[4];
        #pragma unroll
        for (int rr = 0; rr < 4; rr++) {
            float mx = fmaxf(fmaxf(s[0][rr], s[1][rr]), fmaxf(s[2][rr], s[3][rr])) * 0.125f;
            #pragma unroll
            for (int off2 = 1; off2 < 16; off2 <<= 1) mx = fmaxf(mx, __shfl_xor(mx, off2, 64));
            const float mn = fmaxf(m_r[rr], mx);
            float ps = 0.f;
            #pragma unroll
            for (int j = 0; j < 4; j++) {
                const float e = __expf(s[j][rr] * 0.125f - mn);
                s[j][rr] = e; ps += e;
            }
            #pragma unroll
            for (int off2 = 1; off2 < 16; off2 <<= 1) ps += __shfl_xor(ps, off2, 64);
            alpha[rr] = __expf(m_r[rr] - mn);
            l_r[rr] = l_r[rr] * alpha[rr] + ps;
            m_r[rr] = mn;
        }
        #pragma unroll
        for (int j = 0; j < 4; j++)
            #pragma unroll
            for (int rr = 0; rr < 4; rr++)
                Pme[(quad * 4 + rr) * 80 + j * 16 + r16] = (bf16)s[j][rr];
        __asm__ volatile("s_waitcnt lgkmcnt(0)" ::: "memory");
        bf16x8 afp[2];
        #pragma unroll
        for (int st = 0; st < 2; st++)
            afp[st] = *(const bf16x8*)(Pme + r16 * 80 + st * 32 + quad * 8);
        #pragma unroll
        for (int jd = 0; jd < 4; jd++)
            #pragma unroll
            for (int rr = 0; rr < 4; rr++) oacc[jd][rr] *= alpha[rr];
        #pragma unroll
        for (int jd = 0; jd < 4; jd++) {
            bf16x8 b0 = *(const bf16x8*)(Vt + 0 * 2048 + (jd * 16 + r16) * 32 + quad * 8);
            bf16x8 b1 = *(const bf16x8*)(Vt + 1 * 2048 + (jd * 16 + r16) * 32 + quad * 8);
            oacc[jd] = __builtin_amdgcn_mfma_f32_16x16x32_bf16(afp[0], b0, oacc[jd], 0, 0, 0);
            oacc[jd] = __builtin_amdgcn_mfma_f32_16x16x32_bf16(afp[1], b1, oacc[jd], 0, 0, 0);
        }
    }
    #pragma unroll
    for (int rr = 0; rr < 4; rr++) {
        const float inv = 1.f / l_r[rr];
        const size_t base = ((size_t)b * 1024 + qt * 64 + wq * 16 + quad * 4 + rr) * 1024 + hh * 64;
        #pragma unroll
        for (int jd = 0; jd < 4; jd++)
            o[base + jd * 16 + r16] = (bf16)(oacc[jd][rr] * inv);
    }
}

// ---------------------------------------------------------------- swiglu: g = silu(x1)*x2, K-padded to 2816 w/ zeros
__global__ void swiglu_kernel(const bf16* __restrict__ x12, bf16* __restrict__ g)
{
    const int kk = blockIdx.x * 256 + threadIdx.x;
    const int row = blockIdx.y;
    if (kk >= FFNP) return;
    float gv = 0.f;
    if (kk < FFN_) {
        const float a  = (float)x12[(size_t)row * X12N + kk];
        const float b2 = (float)x12[(size_t)row * X12N + FFN_ + kk];
        gv = a * b2 / (1.f + __expf(-a));
    }
    g[(size_t)row * FFNP + kk] = (bf16)gv;
}

// ---------------------------------------------------------------- final linear (K=1024 -> 32) + unpatchify
__global__ __launch_bounds__(256) void final_head(
    const bf16* __restrict__ hn, const float* __restrict__ fw, const float* __restrict__ fb,
    float* __restrict__ out)
{
    __shared__ float hs[1024];
    const int row = blockIdx.x, t = threadIdx.x;
    #pragma unroll
    for (int r = 0; r < 4; r++) hs[t + r * 256] = (float)hn[(size_t)row * 1024 + t + r * 256];
    __syncthreads();
    const int o = t >> 3, s = t & 7;
    float acc = 0.f;
    const float* wr = fw + (size_t)o * 1024 + s * 128;
    const float* hb = hs + s * 128;
    for (int e = 0; e < 128; e++) acc += hb[e] * wr[e];
    #pragma unroll
    for (int off = 1; off < 8; off <<= 1) acc += __shfl_xor(acc, off, 64);
    if (s == 0) {
        acc += fb[o];
        const int b = row >> 10, n = row & 1023;
        const int hp = n >> 4, wp = n & 15;
        const int ph = o >> 3, pw = (o >> 1) & 3, c = o & 1;
        out[((size_t)(b * 2 + c) * 256 + hp * 4 + ph) * 64 + wp * 4 + pw] = acc;
    }
}

// ================================================================ launch
extern "C" void kernel_launch(void* const* d_in, const int* in_sizes, int n_in,
                              void* d_out, int out_size, void* d_ws, size_t ws_size,
                              hipStream_t stream)
{
    const float* x       = (const float*)d_in[0];
    const float* t_in    = (const float*)d_in[1];
    const float* patch_w = (const float*)d_in[2];
    const float* patch_b = (const float*)d_in[3];
    const float* t_w     = (const float*)d_in[4];
    const float* t_b     = (const float*)d_in[5];
    const float* norm1_w = (const float*)d_in[6];
    const float* qkv_w   = (const float*)d_in[7];
    const float* qkv_b   = (const float*)d_in[8];
    const float* qn_w    = (const float*)d_in[9];
    const float* kn_w    = (const float*)d_in[10];
    const float* proj_w  = (const float*)d_in[11];
    const float* proj_b  = (const float*)d_in[12];
    const float* norm2_w = (const float*)d_in[13];
    const float* w12_w   = (const float*)d_in[14];
    const float* w12_b   = (const float*)d_in[15];
    const float* w3_w    = (const float*)d_in[16];
    const float* w3_b    = (const float*)d_in[17];
    const float* ada_w   = (const float*)d_in[18];
    const float* ada_b   = (const float*)d_in[19];
    const float* fnorm_w = (const float*)d_in[20];
    const float* flin_w  = (const float*)d_in[21];
    const float* flin_b  = (const float*)d_in[22];
    const float* fada_w  = (const float*)d_in[23];
    const float* fada_b  = (const float*)d_in[24];

    char* ws = (char*)d_ws;
    size_t off = 0;
    auto alloc = [&](size_t nbytes) { char* p = ws + off; off += (nbytes + 255) & ~(size_t)255; return p; };
    float* h     = (float*)alloc((size_t)TOKS * 1024 * 4);    // residual stream fp32
    float* cs    = (float*)alloc(8 * 1024 * 4);               // silu(t-emb)
    float* ada   = (float*)alloc(8 * 6144 * 4);
    float* fada  = (float*)alloc(8 * 2048 * 4);
    bf16*  hn    = (bf16*)alloc((size_t)TOKS * 1024 * 2);
    char*  U1    =         alloc((size_t)TOKS * X12N * 2);    // q,k,v,o during attn; x12 during FFN
    bf16*  qb    = (bf16*)U1;
    bf16*  kb    = qb + (size_t)TOKS * 1024;
    bf16*  vb    = kb + (size_t)TOKS * 1024;   // [bh][d][n] (pre-transposed)
    bf16*  ob    = vb + (size_t)TOKS * 1024;
    bf16*  x12   = (bf16*)U1;
    bf16*  g     = (bf16*)alloc((size_t)TOKS * FFNP * 2);
    bf16*  wqkvb = (bf16*)alloc((size_t)3072 * 1024 * 2);
    bf16*  wprjb = (bf16*)alloc((size_t)1024 * 1024 * 2);
    bf16*  w12b  = (bf16*)alloc((size_t)X12N * 1024 * 2);
    bf16*  w3p   = (bf16*)alloc((size_t)1024 * FFNP * 2);
    (void)ws_size; (void)in_sizes; (void)n_in; (void)out_size;

    small_gemm<<<dim3(1024 / 4), 256, 0, stream>>>(nullptr, t_in, t_w, t_b, cs, 1024, 256, 1, 1);
    patch_embed<<<dim3(TOKS), 256, 0, stream>>>(x, patch_w, patch_b, h);

    for (int d = 0; d < 8; d++) {
        small_gemm<<<dim3(6144 / 4), 256, 0, stream>>>(cs, nullptr,
            ada_w + (size_t)d * 6144 * 1024, ada_b + (size_t)d * 6144, ada, 6144, 1024, 0, 0);
        norm_mod<<<dim3(TOKS), 256, 0, stream>>>(h, norm1_w + (size_t)d * 1024, ada, 0, 1024, 6144, hn);
        conv_bf16<<<dim3(3072 * 1024 / 4 / 256), 256, 0, stream>>>(qkv_w + (size_t)d * 3072 * 1024, wqkvb, 3072 * 1024);
        gemm256<<<dim3(3072 / 256, 32), 512, 0, stream>>>(hn,
            wqkvb, qkv_b + (size_t)d * 3072, 1024, 3072, EPI_QKV,
            nullptr, 0, qb, kb, vb, nullptr, nullptr, 0);
        rope_qk<<<dim3(256, 128), 256, 0, stream>>>(qb, kb, qn_w + (size_t)d * 64, kn_w + (size_t)d * 64);
        attn_kernel<<<dim3(16, 128), 256, 0, stream>>>(qb, kb, vb, ob);
        conv_bf16<<<dim3(1024 * 1024 / 4 / 256), 256, 0, stream>>>(proj_w + (size_t)d * 1024 * 1024, wprjb, 1024 * 1024);
        gemm256<<<dim3(1024 / 256, 32), 512, 0, stream>>>(ob,
            wprjb, proj_b + (size_t)d * 1024, 1024, 1024, EPI_RESID,
            nullptr, 0, nullptr, nullptr, nullptr, h, ada + 2048, 6144);
        norm_mod<<<dim3(TOKS), 256, 0, stream>>>(h, norm2_w + (size_t)d * 1024, ada, 3072, 4096, 6144, hn);
        conv_bf16<<<dim3(X12N * 1024 / 4 / 256), 256, 0, stream>>>(w12_w + (size_t)d * X12N * 1024, w12b, X12N * 1024);
        gemm256<<<dim3((X12N + 255) / 256, 32), 512, 0, stream>>>(hn,
            w12b, w12_b + (size_t)d * X12N, 1024, X12N, EPI_BF16,
            x12, X12N, nullptr, nullptr, nullptr, nullptr, nullptr, 0);
        swiglu_kernel<<<dim3(FFNP / 256, TOKS), 256, 0, stream>>>(x12, g);
        conv_pad_w3<<<dim3(FFNP / 256, 1024), 256, 0, stream>>>(w3_w + (size_t)d * 1024 * FFN_, w3p);
        gemm256<<<dim3(1024 / 256, 32), 512, 0, stream>>>(g,
            w3p, w3_b + (size_t)d * 1024, FFNP, 1024, EPI_RESID,
            nullptr, 0, nullptr, nullptr, nullptr, h, ada + 5120, 6144);
    }

    small_gemm<<<dim3(2048 / 4), 256, 0, stream>>>(cs, nullptr, fada_w, fada_b, fada, 2048, 1024, 0, 0);
    norm_mod<<<dim3(TOKS), 256, 0, stream>>>(h, fnorm_w, fada, 0, 1024, 2048, hn);
    final_head<<<dim3(TOKS), 256, 0, stream>>>(hn, flin_w, flin_b, (float*)d_out);
}

// Round 2
// 4995.791 us; speedup vs baseline: 1.1125x; 1.1125x over previous
//
#include <hip/hip_runtime.h>
#include <stdint.h>

typedef __bf16 bf16;
typedef __attribute__((ext_vector_type(8))) __bf16 bf16x8;
typedef __attribute__((ext_vector_type(4))) float floatx4;

#define NTOK   1024     // tokens per batch (N)
#define TOKS   8192     // B*N
#define HID_   1024
#define FFN_   2730
#define FFNP   2816     // FFN padded to mult of 128
#define X12N   5460     // 2*FFN

#define EPI_BF16  0
#define EPI_QKV   1
#define EPI_RESID 2

// ---------------------------------------------------------------- fp32 -> bf16 weight conversion
__global__ __launch_bounds__(256) void conv_bf16(const float* __restrict__ in, bf16* __restrict__ out, int n)
{
    const int i = (blockIdx.x * 256 + threadIdx.x) * 4;
    if (i >= n) return;
    const float4 v = *(const float4*)(in + i);
    out[i + 0] = (bf16)v.x; out[i + 1] = (bf16)v.y;
    out[i + 2] = (bf16)v.z; out[i + 3] = (bf16)v.w;
}

// w3 (1024 x 2730) fp32 -> (1024 x 2816) bf16 zero-padded
__global__ void conv_pad_w3(const float* __restrict__ w3, bf16* __restrict__ w3p)
{
    const int kk = blockIdx.x * 256 + threadIdx.x;
    const int row = blockIdx.y;
    if (kk >= FFNP) return;
    w3p[(size_t)row * FFNP + kk] = (kk < FFN_) ? (bf16)w3[(size_t)row * FFN_ + kk] : (bf16)0.f;
}

// ---------------------------------------------------------------- shared GEMM machinery
#define GLL(src, dst) __builtin_amdgcn_global_load_lds( \
    (const __attribute__((address_space(1))) void*)(src), \
    (__attribute__((address_space(3))) void*)(dst), 16, 0, 0)

#define PHTAIL(...) { __builtin_amdgcn_s_barrier(); \
    asm volatile("s_waitcnt lgkmcnt(0)" ::: "memory"); \
    __builtin_amdgcn_sched_barrier(0); \
    __builtin_amdgcn_s_setprio(1); __VA_ARGS__; __builtin_amdgcn_s_setprio(0); \
    __builtin_amdgcn_s_barrier(); }

#define XCD_SWZ(wg, nwg) { \
    const int q8 = (nwg) >> 3, r8 = (nwg) & 7; \
    const int xcd = (wg) & 7, pos = (wg) >> 3; \
    wg = (xcd < r8 ? xcd * (q8 + 1) : r8 * (q8 + 1) + (xcd - r8) * q8) + pos; }

// ================================================================ GEMM 256x256 tile (w12)
// 512 thr = 8 waves (2x4), BK=64, 2-buffer 8-phase, counted vmcnt, each frag read once.
#define STAGE_A(bufi, hi, tile) GLL(pA[hi] + (size_t)(tile) * 64, As + (bufi) * 16384 + ((hi) * 512 + t) * 8)
#define STAGE_B(bufi, hi, tile) GLL(pB[hi] + (size_t)(tile) * 64, Bs + (bufi) * 16384 + ((hi) * 512 + t) * 8)

#define LOADA(bufi, qm) { _Pragma("unroll") for (int mf = 0; mf < 4; mf++) { \
    a[mf][0] = *(const bf16x8*)(As + (bufi) * 16384 + (qm) * 8192 + arow64 + mf * 1024 + swz0); \
    a[mf][1] = *(const bf16x8*)(As + (bufi) * 16384 + (qm) * 8192 + arow64 + mf * 1024 + swz1); } }

#define LOADB(bufi, qn, breg) { _Pragma("unroll") for (int nf = 0; nf < 2; nf++) { \
    breg[nf][0] = *(const bf16x8*)(Bs + (bufi) * 16384 + (qn) * 8192 + brow64 + nf * 1024 + swz0); \
    breg[nf][1] = *(const bf16x8*)(Bs + (bufi) * 16384 + (qn) * 8192 + brow64 + nf * 1024 + swz1); } }

#define MM2(qm, qn, breg) { _Pragma("unroll") for (int mf = 0; mf < 4; mf++) \
    _Pragma("unroll") for (int nf = 0; nf < 2; nf++) { \
    acc[qm][qn][mf][nf] = __builtin_amdgcn_mfma_f32_16x16x32_bf16(a[mf][0], breg[nf][0], acc[qm][qn][mf][nf], 0, 0, 0); \
    acc[qm][qn][mf][nf] = __builtin_amdgcn_mfma_f32_16x16x32_bf16(a[mf][1], breg[nf][1], acc[qm][qn][mf][nf], 0, 0, 0); } }

__global__ __launch_bounds__(512, 2) void gemm256(
    const bf16* __restrict__ A, const bf16* __restrict__ Bm, const float* __restrict__ bias,
    int K, int Nreal, int epi,
    bf16* __restrict__ outb, int ldo,
    bf16* __restrict__ qo, bf16* __restrict__ ko, bf16* __restrict__ vo,
    float* __restrict__ hres, const float* __restrict__ gate, int gstride)
{
    __shared__ __align__(16) bf16 As[2 * 16384];
    __shared__ __align__(16) bf16 Bs[2 * 16384];
    const int t = threadIdx.x;

    const int gx = gridDim.x;
    int wg = blockIdx.y * gx + blockIdx.x;
    { const int nwg = gx * gridDim.y; XCD_SWZ(wg, nwg); }
    const int M0 = (wg / gx) * 256, N0 = (wg % gx) * 256;
    const int Nlast = Nreal - 1;

    const int lane = t & 63, w = t >> 6;
    const int wm = w >> 2, wn = w & 3;
    const int quad = lane >> 4, r16 = lane & 15;

    const int rS = t >> 3;
    const int cswS = (t & 7) ^ (rS & 7);
    const bf16* pA[4]; const bf16* pB[4];
    #pragma unroll
    for (int hi = 0; hi < 4; hi++) {
        pA[hi] = A + (size_t)(M0 + hi * 64 + rS) * K + cswS * 8;
        int nb = N0 + hi * 64 + rS; if (nb > Nlast) nb = Nlast;
        pB[hi] = Bm + (size_t)nb * K + cswS * 8;
    }

    const int arow64 = (wm * 64 + r16) * 64;
    const int brow64 = (wn * 32 + r16) * 64;
    const int swz0 = ((0 * 4 + quad) ^ (r16 & 7)) * 8;
    const int swz1 = ((1 * 4 + quad) ^ (r16 & 7)) * 8;

    floatx4 acc[2][2][4][2];
    const floatx4 zero = {0.f, 0.f, 0.f, 0.f};
    #pragma unroll
    for (int i0 = 0; i0 < 2; i0++)
        #pragma unroll
        for (int i1 = 0; i1 < 2; i1++)
            #pragma unroll
            for (int i2 = 0; i2 < 4; i2++)
                #pragma unroll
                for (int i3 = 0; i3 < 2; i3++) acc[i0][i1][i2][i3] = zero;
    bf16x8 a[4][2], b0[2][2], b1[2][2];

    const int NT = K >> 6;
    const int NI = NT >> 1;

    // prologue: tile0 full + bottom(A0,A1,B0,B1) of tile1
    STAGE_A(0, 0, 0); STAGE_A(0, 1, 0);
    STAGE_B(0, 0, 0); STAGE_B(0, 1, 0);
    STAGE_B(0, 2, 0); STAGE_B(0, 3, 0);
    STAGE_A(0, 2, 0); STAGE_A(0, 3, 0);
    STAGE_A(1, 0, 1); STAGE_A(1, 1, 1);
    STAGE_B(1, 0, 1); STAGE_B(1, 1, 1);
    asm volatile("s_waitcnt vmcnt(4)" ::: "memory");
    __builtin_amdgcn_s_barrier();

    for (int it = 0; it < NI; ++it) {
        const bool last = (it == NI - 1);
        const int to = 2 * it + 1, te2 = 2 * it + 2, to2 = 2 * it + 3;
        // ---- even tile (buf0)
        LOADA(0, 0); LOADB(0, 0, b0);
        STAGE_A(1, 2, to); STAGE_A(1, 3, to);
        PHTAIL(MM2(0, 0, b0));
        LOADB(0, 1, b1);
        STAGE_B(1, 2, to); STAGE_B(1, 3, to);
        PHTAIL(MM2(0, 1, b1));
        LOADA(0, 1);
        if (!last) { STAGE_A(0, 0, te2); STAGE_A(0, 1, te2); }
        PHTAIL(MM2(1, 0, b0));
        if (!last) { STAGE_B(0, 0, te2); STAGE_B(0, 1, te2);
                     asm volatile("s_waitcnt vmcnt(4)" ::: "memory"); }
        else       { asm volatile("s_waitcnt vmcnt(0)" ::: "memory"); }
        PHTAIL(MM2(1, 1, b1));
        // ---- odd tile (buf1)
        LOADA(1, 0); LOADB(1, 0, b0);
        if (!last) { STAGE_A(0, 2, te2); STAGE_A(0, 3, te2); }
        PHTAIL(MM2(0, 0, b0));
        LOADB(1, 1, b1);
        if (!last) { STAGE_B(0, 2, te2); STAGE_B(0, 3, te2); }
        PHTAIL(MM2(0, 1, b1));
        LOADA(1, 1);
        if (!last) { STAGE_A(1, 0, to2); STAGE_A(1, 1, to2); }
        PHTAIL(MM2(1, 0, b0));
        if (!last) { STAGE_B(1, 0, to2); STAGE_B(1, 1, to2);
                     asm volatile("s_waitcnt vmcnt(4)" ::: "memory"); }
        PHTAIL(MM2(1, 1, b1));
    }

    #pragma unroll
    for (int qm = 0; qm < 2; qm++)
    #pragma unroll
    for (int mf = 0; mf < 4; mf++) {
        const int rbase = M0 + qm * 128 + wm * 64 + mf * 16 + quad * 4;
        #pragma unroll
        for (int qn = 0; qn < 2; qn++)
        #pragma unroll
        for (int nf = 0; nf < 2; nf++) {
            const int col = N0 + qn * 128 + wn * 32 + nf * 16 + r16;
            if (col >= Nreal) continue;
            const float bv = bias[col];
            const floatx4 av = acc[qm][qn][mf][nf];
            if (epi == EPI_BF16) {
                #pragma unroll
                for (int rr = 0; rr < 4; rr++)
                    outb[(size_t)(rbase + rr) * ldo + col] = (bf16)(av[rr] + bv);
            } else if (epi == EPI_QKV) {
                const int s = col >> 10, hh = (col >> 6) & 15, dd = col & 63;
                #pragma unroll
                for (int rr = 0; rr < 4; rr++) {
                    const int row = rbase + rr;
                    const int bb = row >> 10, n = row & 1023;
                    const float vv = av[rr] + bv;
                    if (s == 0)      qo[((size_t)(bb * 16 + hh) * 1024 + n) * 64 + dd] = (bf16)vv;
                    else if (s == 1) ko[((size_t)(bb * 16 + hh) * 1024 + n) * 64 + dd] = (bf16)vv;
                    else             vo[((size_t)(bb * 16 + hh) * 64 + dd) * 1024 + n] = (bf16)vv;
                }
            } else {
                #pragma unroll
                for (int rr = 0; rr < 4; rr++) {
                    const int row = rbase + rr;
                    const int bb = row >> 10;
                    hres[(size_t)row * 1024 + col] += gate[(size_t)bb * gstride + col] * (av[rr] + bv);
                }
            }
        }
    }
}

// ================================================================ GEMM 128x256 tile (qkv / proj / w3)
// 512 thr = 8 waves (2x4), per-wave 64x64 out, BK=64, 3-buffer, 2 phases per K-tile.
// Tile T staged (3+3 GLLs) during tile T-2's phases into buf T%3; vmcnt(6) once/K-tile.
#define STA1(bufi, hi, tile) GLL(pA[hi] + (size_t)(tile) * 64, As + (bufi) * 8192  + ((hi) * 512 + t) * 8)
#define STB1(bufi, hi, tile) GLL(pB[hi] + (size_t)(tile) * 64, Bs + (bufi) * 16384 + ((hi) * 512 + t) * 8)

#define LA1(bufi) { _Pragma("unroll") for (int mf = 0; mf < 4; mf++) { \
    a[mf][0] = *(const bf16x8*)(As + (bufi) * 8192 + arow64 + mf * 1024 + swz0); \
    a[mf][1] = *(const bf16x8*)(As + (bufi) * 8192 + arow64 + mf * 1024 + swz1); } }

#define LB1(bufi, qn, breg) { _Pragma("unroll") for (int nf = 0; nf < 2; nf++) { \
    breg[nf][0] = *(const bf16x8*)(Bs + (bufi) * 16384 + (qn) * 8192 + brow64 + nf * 1024 + swz0); \
    breg[nf][1] = *(const bf16x8*)(Bs + (bufi) * 16384 + (qn) * 8192 + brow64 + nf * 1024 + swz1); } }

#define MM1(qn, breg) { _Pragma("unroll") for (int mf = 0; mf < 4; mf++) \
    _Pragma("unroll") for (int nf = 0; nf < 2; nf++) { \
    acc[qn][mf][nf] = __builtin_amdgcn_mfma_f32_16x16x32_bf16(a[mf][0], breg[nf][0], acc[qn][mf][nf], 0, 0, 0); \
    acc[qn][mf][nf] = __builtin_amdgcn_mfma_f32_16x16x32_bf16(a[mf][1], breg[nf][1], acc[qn][mf][nf], 0, 0, 0); } }

__global__ __launch_bounds__(512, 2) void gemm128(
    const bf16* __restrict__ A, const bf16* __restrict__ Bm, const float* __restrict__ bias,
    int K, int Nreal, int epi,
    bf16* __restrict__ outb, int ldo,
    bf16* __restrict__ qo, bf16* __restrict__ ko, bf16* __restrict__ vo,
    float* __restrict__ hres, const float* __restrict__ gate, int gstride)
{
    __shared__ __align__(16) bf16 As[3 * 8192];    // 3 bufs x 128x64
    __shared__ __align__(16) bf16 Bs[3 * 16384];   // 3 bufs x 256x64
    const int t = threadIdx.x;

    const int gx = gridDim.x;
    int wg = blockIdx.y * gx + blockIdx.x;
    { const int nwg = gx * gridDim.y; XCD_SWZ(wg, nwg); }
    const int M0 = (wg / gx) * 128, N0 = (wg % gx) * 256;
    const int Nlast = Nreal - 1;

    const int lane = t & 63, w = t >> 6;
    const int wm = w >> 2, wn = w & 3;
    const int quad = lane >> 4, r16 = lane & 15;

    const int rS = t >> 3;
    const int cswS = (t & 7) ^ (rS & 7);
    const bf16* pA[2]; const bf16* pB[4];
    #pragma unroll
    for (int hi = 0; hi < 2; hi++)
        pA[hi] = A + (size_t)(M0 + hi * 64 + rS) * K + cswS * 8;
    #pragma unroll
    for (int hi = 0; hi < 4; hi++) {
        int nb = N0 + hi * 64 + rS; if (nb > Nlast) nb = Nlast;
        pB[hi] = Bm + (size_t)nb * K + cswS * 8;
    }

    const int arow64 = (wm * 64 + r16) * 64;
    const int brow64 = (wn * 32 + r16) * 64;
    const int swz0 = ((0 * 4 + quad) ^ (r16 & 7)) * 8;
    const int swz1 = ((1 * 4 + quad) ^ (r16 & 7)) * 8;

    floatx4 acc[2][4][2];
    const floatx4 zero = {0.f, 0.f, 0.f, 0.f};
    #pragma unroll
    for (int i0 = 0; i0 < 2; i0++)
        #pragma unroll
        for (int i1 = 0; i1 < 4; i1++)
            #pragma unroll
            for (int i2 = 0; i2 < 2; i2++) acc[i0][i1][i2] = zero;
    bf16x8 a[4][2], b0[2][2], b1[2][2];

    const int NT = K >> 6;

    // prologue: stage tiles 0 (buf0) and 1 (buf1) fully
    STA1(0, 0, 0); STA1(0, 1, 0);
    STB1(0, 0, 0); STB1(0, 1, 0); STB1(0, 2, 0); STB1(0, 3, 0);
    STA1(1, 0, 1); STA1(1, 1, 1);
    STB1(1, 0, 1); STB1(1, 1, 1); STB1(1, 2, 1); STB1(1, 3, 1);
    asm volatile("s_waitcnt vmcnt(6)" ::: "memory");   // tile0 landed; tile1 in flight
    __builtin_amdgcn_s_barrier();

    int bufR = 0;
    for (int tt = 0; tt < NT; ++tt) {
        const int ts = tt + 2;
        const int bufS = (bufR == 0) ? 2 : bufR - 1;   // (tt+2)%3
        const bool st = (ts < NT);
        // phase even: A + B(qn=0) reads, stage {A0,A1,B0} of tile ts
        LA1(bufR); LB1(bufR, 0, b0);
        if (st) { STA1(bufS, 0, ts); STA1(bufS, 1, ts); STB1(bufS, 0, ts); }
        PHTAIL(MM1(0, b0));
        // phase odd: B(qn=1) reads, stage {B1,B2,B3} of tile ts, then wait
        LB1(bufR, 1, b1);
        if (st) { STB1(bufS, 1, ts); STB1(bufS, 2, ts); STB1(bufS, 3, ts); }
        if (tt < NT - 2)       { asm volatile("s_waitcnt vmcnt(6)" ::: "memory"); }
        else if (tt == NT - 2) { asm volatile("s_waitcnt vmcnt(0)" ::: "memory"); }
        PHTAIL(MM1(1, b1));
        bufR = (bufR == 2) ? 0 : bufR + 1;
    }

    // epilogue: row = M0 + wm*64 + mf*16 + quad*4 + rr; col = N0 + qn*128 + wn*32 + nf*16 + r16
    #pragma unroll
    for (int mf = 0; mf < 4; mf++) {
        const int rbase = M0 + wm * 64 + mf * 16 + quad * 4;
        #pragma unroll
        for (int qn = 0; qn < 2; qn++)
        #pragma unroll
        for (int nf = 0; nf < 2; nf++) {
            const int col = N0 + qn * 128 + wn * 32 + nf * 16 + r16;
            if (col >= Nreal) continue;
            const float bv = bias[col];
            const floatx4 av = acc[qn][mf][nf];
            if (epi == EPI_BF16) {
                #pragma unroll
                for (int rr = 0; rr < 4; rr++)
                    outb[(size_t)(rbase + rr) * ldo + col] = (bf16)(av[rr] + bv);
            } else if (epi == EPI_QKV) {
                const int s = col >> 10, hh = (col >> 6) & 15, dd = col & 63;
                #pragma unroll
                for (int rr = 0; rr < 4; rr++) {
                    const int row = rbase + rr;
                    const int bb = row >> 10, n = row & 1023;
                    const float vv = av[rr] + bv;
                    if (s == 0)      qo[((size_t)(bb * 16 + hh) * 1024 + n) * 64 + dd] = (bf16)vv;
                    else if (s == 1) ko[((size_t)(bb * 16 + hh) * 1024 + n) * 64 + dd] = (bf16)vv;
                    else             vo[((size_t)(bb * 16 + hh) * 64 + dd) * 1024 + n] = (bf16)vv;
                }
            } else {
                #pragma unroll
                for (int rr = 0; rr < 4; rr++) {
                    const int row = rbase + rr;
                    const int bb = row >> 10;
                    hres[(size_t)row * 1024 + col] += gate[(size_t)bb * gstride + col] * (av[rr] + bv);
                }
            }
        }
    }
}

// ---------------------------------------------------------------- small GEMM (8 x N) = A(8 x K) * W(N x K)^T
__global__ __launch_bounds__(256) void small_gemm(
    const float* __restrict__ Aws, const float* __restrict__ t_in,
    const float* __restrict__ W, const float* __restrict__ bias,
    float* __restrict__ out, int N, int K, int mode, int dosilu)
{
    const int w = threadIdx.x >> 6, lane = threadIdx.x & 63;
    const int col = blockIdx.x * 4 + w;
    float acc[8];
    #pragma unroll
    for (int bb = 0; bb < 8; bb++) acc[bb] = 0.f;
    float tb[8];
    if (mode == 1) {
        #pragma unroll
        for (int bb = 0; bb < 8; bb++) tb[bb] = t_in[bb];
    }
    for (int kk = lane; kk < K; kk += 64) {
        const float wv = W[(size_t)col * K + kk];
        if (mode == 1) {
            const float f = __expf(-(float)(kk & 127) * (9.21034037198f / 128.f));
            #pragma unroll
            for (int bb = 0; bb < 8; bb++) {
                const float arg = tb[bb] * f;
                const float e = (kk < 128) ? cosf(arg) : sinf(arg);
                acc[bb] += e * wv;
            }
        } else {
            #pragma unroll
            for (int bb = 0; bb < 8; bb++) acc[bb] += Aws[(size_t)bb * 1024 + kk] * wv;
        }
    }
    #pragma unroll
    for (int bb = 0; bb < 8; bb++) {
        float v2 = acc[bb];
        #pragma unroll
        for (int off = 32; off; off >>= 1) v2 += __shfl_xor(v2, off, 64);
        acc[bb] = v2;
    }
    if (lane == 0) {
        const float bv = bias[col];
        #pragma unroll
        for (int bb = 0; bb < 8; bb++) {
            float vv = acc[bb] + bv;
            if (dosilu) vv = vv / (1.f + __expf(-vv));
            out[(size_t)bb * N + col] = vv;
        }
    }
}

// ---------------------------------------------------------------- patch embed + pos embed -> h (fp32)
__global__ __launch_bounds__(256) void patch_embed(
    const float* __restrict__ x, const float* __restrict__ pw, const float* __restrict__ pb,
    float* __restrict__ h)
{
    __shared__ float xs[32];
    const int row = blockIdx.x, t = threadIdx.x;
    const int b = row >> 10, n = row & 1023;
    const int hp = n >> 4, wp = n & 15;
    if (t < 32) {
        const int c = t >> 4, ph = (t >> 2) & 3, pq = t & 3;
        xs[t] = x[((size_t)(b * 2 + c) * 256 + hp * 4 + ph) * 64 + wp * 4 + pq];
    }
    __syncthreads();
    #pragma unroll
    for (int rep = 0; rep < 4; rep++) {
        const int o = t + rep * 256;
        const float* wrow = pw + (size_t)o * 32;
        float acc = pb[o];
        #pragma unroll
        for (int e = 0; e < 32; e++) acc += xs[e] * wrow[e];
        const int seg = o >> 8, oo = o & 255;
        const float om = __expf(-(float)oo * (9.21034037198f / 256.f));
        const float pos = (seg < 2) ? (float)wp : (float)hp;
        const float arg = pos * om;
        const float pe = ((seg & 1) == 0) ? sinf(arg) : cosf(arg);
        h[(size_t)row * 1024 + o] = acc + pe;
    }
}

// ---------------------------------------------------------------- rmsnorm + modulate -> bf16
__global__ __launch_bounds__(256) void norm_mod(
    const float* __restrict__ h, const float* __restrict__ w,
    const float* __restrict__ ada, int sh_off, int sc_off, int stride,
    bf16* __restrict__ out)
{
    __shared__ float red[4];
    const int row = blockIdx.x, t = threadIdx.x;
    const int b = row >> 10;
    const float4 xv = ((const float4*)(h + (size_t)row * 1024))[t];
    float ss = xv.x * xv.x + xv.y * xv.y + xv.z * xv.z + xv.w * xv.w;
    #pragma unroll
    for (int off = 32; off; off >>= 1) ss += __shfl_xor(ss, off, 64);
    if ((t & 63) == 0) red[t >> 6] = ss;
    __syncthreads();
    const float total = red[0] + red[1] + red[2] + red[3];
    const float rms = rsqrtf(total * (1.f / 1024.f) + 1e-6f);
    const float* sh = ada + (size_t)b * stride + sh_off;
    const float* sc = ada + (size_t)b * stride + sc_off;
    const float vals[4] = {xv.x, xv.y, xv.z, xv.w};
    #pragma unroll
    for (int e = 0; e < 4; e++) {
        const int c2 = t * 4 + e;
        const float vv = vals[e] * rms * w[c2] * (1.f + sc[c2]) + sh[c2];
        out[(size_t)row * 1024 + c2] = (bf16)vv;
    }
}

// ---------------------------------------------------------------- qk rmsnorm + RoPE (in place), 4 rows/block
__global__ __launch_bounds__(256) void rope_qk(
    bf16* __restrict__ q, bf16* __restrict__ k,
    const float* __restrict__ qw, const float* __restrict__ kw)
{
    const int n = blockIdx.x * 4 + (threadIdx.x >> 6);
    const int bh = blockIdx.y, d = threadIdx.x & 63;
    const size_t idx = ((size_t)bh * 1024 + n) * 64 + d;
    const float qv = (float)q[idx], kv = (float)k[idx];
    float sq = qv * qv, sk = kv * kv;
    #pragma unroll
    for (int off = 32; off; off >>= 1) { sq += __shfl_xor(sq, off, 64); sk += __shfl_xor(sk, off, 64); }
    const float rq = rsqrtf(sq * (1.f / 64.f) + 1e-6f);
    const float rk = rsqrtf(sk * (1.f / 64.f) + 1e-6f);
    const float qn = qv * rq * qw[d];
    const float kn = kv * rk * kw[d];
    const int j = (d & 31) >> 1;
    const float freq = __expf(-(float)j * (9.21034037198f / 16.f));
    const float pos = (d < 32) ? (float)(n >> 4) : (float)(n & 15);
    const float ang = pos * freq;
    const float cv = cosf(ang), sv = sinf(ang);
    const float qp = __shfl_xor(qn, 1, 64);
    const float kp = __shfl_xor(kn, 1, 64);
    const float qo = qn * cv + ((d & 1) ? qp : -qp) * sv;
    const float ko = kn * cv + ((d & 1) ? kp : -kp) * sv;
    q[idx] = (bf16)qo;
    k[idx] = (bf16)ko;
}

// ---------------------------------------------------------------- MFMA flash attention
__global__ __launch_bounds__(256) void attn_kernel(
    const bf16* __restrict__ q, const bf16* __restrict__ k, const bf16* __restrict__ v,
    bf16* __restrict__ o)
{
    __shared__ __align__(16) bf16 Qs[2 * 64 * 32];
    __shared__ __align__(16) bf16 Ks[2 * 64 * 32];
    __shared__ __align__(16) bf16 Vt[2 * 64 * 32];
    __shared__ __align__(16) bf16 Pw[4 * 16 * 80];
    const int t = threadIdx.x;
    const int l = t & 63, wq = t >> 6;
    const int quad = l >> 4, r16 = l & 15;
    const int qt = blockIdx.x, bh = blockIdx.y;
    const int b = bh >> 4, hh = bh & 15;

    #pragma unroll
    for (int m = 0; m < 2; m++) {
        const bf16* g = q + ((size_t)bh * 1024 + qt * 64 + wq * 16 + (l >> 2)) * 64 + m * 32 + (l & 3) * 8;
        __builtin_amdgcn_global_load_lds((const __attribute__((address_space(1))) void*)g,
            (__attribute__((address_space(3))) void*)(Qs + m * 2048 + wq * 16 * 32 + l * 8), 16, 0, 0);
    }
    __syncthreads();
    bf16x8 afq[2];
    #pragma unroll
    for (int h2 = 0; h2 < 2; h2++)
        afq[h2] = *(const bf16x8*)(Qs + h2 * 2048 + (wq * 16 + r16) * 32 + quad * 8);

    float m_r[4], l_r[4];
    floatx4 oacc[4];
    const floatx4 zero = {0.f, 0.f, 0.f, 0.f};
    #pragma unroll
    for (int rr = 0; rr < 4; rr++) { m_r[rr] = -1e30f; l_r[rr] = 0.f; }
    #pragma unroll
    for (int jd = 0; jd < 4; jd++) oacc[jd] = zero;

    bf16* Pme = Pw + wq * 16 * 80;

    for (int kt = 0; kt < 16; kt++) {
        __syncthreads();
        #pragma unroll
        for (int m = 0; m < 2; m++) {
            const bf16* gk = k + ((size_t)bh * 1024 + kt * 64 + wq * 16 + (l >> 2)) * 64 + m * 32 + (l & 3) * 8;
            __builtin_amdgcn_global_load_lds((const __attribute__((address_space(1))) void*)gk,
                (__attribute__((address_space(3))) void*)(Ks + m * 2048 + wq * 16 * 32 + l * 8), 16, 0, 0);
            const bf16* gv = v + ((size_t)bh * 64 + wq * 16 + (l >> 2)) * 1024 + kt * 64 + m * 32 + (l & 3) * 8;
            __builtin_amdgcn_global_load_lds((const __attribute__((address_space(1))) void*)gv,
                (__attribute__((address_space(3))) void*)(Vt + m * 2048 + wq * 16 * 32 + l * 8), 16, 0, 0);
        }
        __syncthreads();

        floatx4 s[4];
        #pragma unroll
        for (int j = 0; j < 4; j++) {
            bf16x8 k0 = *(const bf16x8*)(Ks + 0 * 2048 + (j * 16 + r16) * 32 + quad * 8);
            bf16x8 k1 = *(const bf16x8*)(Ks + 1 * 2048 + (j * 16 + r16) * 32 + quad * 8);
            s[j] = __builtin_amdgcn_mfma_f32_16x16x32_bf16(afq[0], k0, zero, 0, 0, 0);
            s[j] = __builtin_amdgcn_mfma_f32_16x16x32_bf16(afq[1], k1, s[j], 0, 0, 0);
        }
        float alpha[4];
        #pragma unroll
        for (int rr = 0; rr < 4; rr++) {
            float mx = fmaxf(fmaxf(s[0][rr], s[1][rr]), fmaxf(s[2][rr], s[3][rr])) * 0.125f;
            #pragma unroll
            for (int off2 = 1; off2 < 16; off2 <<= 1) mx = fmaxf(mx, __shfl_xor(mx, off2, 64));
            const float mn = fmaxf(m_r[rr], mx);
            float ps = 0.f;
            #pragma unroll
            for (int j = 0; j < 4; j++) {
                const float e = __expf(s[j][rr] * 0.125f - mn);
                s[j][rr] = e; ps += e;
            }
            #pragma unroll
            for (int off2 = 1; off2 < 16; off2 <<= 1) ps += __shfl_xor(ps, off2, 64);
            alpha[rr] = __expf(m_r[rr] - mn);
            l_r[rr] = l_r[rr] * alpha[rr] + ps;
            m_r[rr] = mn;
        }
        #pragma unroll
        for (int j = 0; j < 4; j++)
            #pragma unroll
            for (int rr = 0; rr < 4; rr++)
                Pme[(quad * 4 + rr) * 80 + j * 16 + r16] = (bf16)s[j][rr];
        __asm__ volatile("s_waitcnt lgkmcnt(0)" ::: "memory");
        bf16x8 afp[2];
        #pragma unroll
        for (int st = 0; st < 2; st++)
            afp[st] = *(const bf16x8*)(Pme + r16 * 80 + st * 32 + quad * 8);
        #pragma unroll
        for (int jd = 0; jd < 4; jd++)
            #pragma unroll
            for (int rr = 0; rr < 4; rr++) oacc[jd][rr] *= alpha[rr];
        #pragma unroll
        for (int jd = 0; jd < 4; jd++) {
            bf16x8 v0 = *(const bf16x8*)(Vt + 0 * 2048 + (jd * 16 + r16) * 32 + quad * 8);
            bf16x8 v1 = *(const bf16x8*)(Vt + 1 * 2048 + (jd * 16 + r16) * 32 + quad * 8);
            oacc[jd] = __builtin_amdgcn_mfma_f32_16x16x32_bf16(afp[0], v0, oacc[jd], 0, 0, 0);
            oacc[jd] = __builtin_amdgcn_mfma_f32_16x16x32_bf16(afp[1], v1, oacc[jd], 0, 0, 0);
        }
    }
    #pragma unroll
    for (int rr = 0; rr < 4; rr++) {
        const float inv = 1.f / l_r[rr];
        const size_t base = ((size_t)b * 1024 + qt * 64 + wq * 16 + quad * 4 + rr) * 1024 + hh * 64;
        #pragma unroll
        for (int jd = 0; jd < 4; jd++)
            o[base + jd * 16 + r16] = (bf16)(oacc[jd][rr] * inv);
    }
}

// ---------------------------------------------------------------- swiglu: g = silu(x1)*x2, K-padded to 2816 w/ zeros
__global__ void swiglu_kernel(const bf16* __restrict__ x12, bf16* __restrict__ g)
{
    const int kk = blockIdx.x * 256 + threadIdx.x;
    const int row = blockIdx.y;
    if (kk >= FFNP) return;
    float gv = 0.f;
    if (kk < FFN_) {
        const float a  = (float)x12[(size_t)row * X12N + kk];
        const float b2 = (float)x12[(size_t)row * X12N + FFN_ + kk];
        gv = a * b2 / (1.f + __expf(-a));
    }
    g[(size_t)row * FFNP + kk] = (bf16)gv;
}

// ---------------------------------------------------------------- final linear (K=1024 -> 32) + unpatchify
__global__ __launch_bounds__(256) void final_head(
    const bf16* __restrict__ hn, const float* __restrict__ fw, const float* __restrict__ fb,
    float* __restrict__ out)
{
    __shared__ float hs[1024];
    const int row = blockIdx.x, t = threadIdx.x;
    #pragma unroll
    for (int r = 0; r < 4; r++) hs[t + r * 256] = (float)hn[(size_t)row * 1024 + t + r * 256];
    __syncthreads();
    const int o = t >> 3, s = t & 7;
    float acc = 0.f;
    const float* wr = fw + (size_t)o * 1024 + s * 128;
    const float* hb = hs + s * 128;
    for (int e = 0; e < 128; e++) acc += hb[e] * wr[e];
    #pragma unroll
    for (int off = 1; off < 8; off <<= 1) acc += __shfl_xor(acc, off, 64);
    if (s == 0) {
        acc += fb[o];
        const int b = row >> 10, n = row & 1023;
        const int hp = n >> 4, wp = n & 15;
        const int ph = o >> 3, pw = (o >> 1) & 3, c = o & 1;
        out[((size_t)(b * 2 + c) * 256 + hp * 4 + ph) * 64 + wp * 4 + pw] = acc;
    }
}

// ================================================================ launch
extern "C" void kernel_launch(void* const* d_in, const int* in_sizes, int n_in,
                              void* d_out, int out_size, void* d_ws, size_t ws_size,
                              hipStream_t stream)
{
    const float* x       = (const float*)d_in[0];
    const float* t_in    = (const float*)d_in[1];
    const float* patch_w = (const float*)d_in[2];
    const float* patch_b = (const float*)d_in[3];
    const float* t_w     = (const float*)d_in[4];
    const float* t_b     = (const float*)d_in[5];
    const float* norm1_w = (const float*)d_in[6];
    const float* qkv_w   = (const float*)d_in[7];
    const float* qkv_b   = (const float*)d_in[8];
    const float* qn_w    = (const float*)d_in[9];
    const float* kn_w    = (const float*)d_in[10];
    const float* proj_w  = (const float*)d_in[11];
    const float* proj_b  = (const float*)d_in[12];
    const float* norm2_w = (const float*)d_in[13];
    const float* w12_w   = (const float*)d_in[14];
    const float* w12_b   = (const float*)d_in[15];
    const float* w3_w    = (const float*)d_in[16];
    const float* w3_b    = (const float*)d_in[17];
    const float* ada_w   = (const float*)d_in[18];
    const float* ada_b   = (const float*)d_in[19];
    const float* fnorm_w = (const float*)d_in[20];
    const float* flin_w  = (const float*)d_in[21];
    const float* flin_b  = (const float*)d_in[22];
    const float* fada_w  = (const float*)d_in[23];
    const float* fada_b  = (const float*)d_in[24];

    char* ws = (char*)d_ws;
    size_t off = 0;
    auto alloc = [&](size_t nbytes) { char* p = ws + off; off += (nbytes + 255) & ~(size_t)255; return p; };
    float* h     = (float*)alloc((size_t)TOKS * 1024 * 4);
    float* cs    = (float*)alloc(8 * 1024 * 4);
    float* ada   = (float*)alloc(8 * 6144 * 4);
    float* fada  = (float*)alloc(8 * 2048 * 4);
    bf16*  hn    = (bf16*)alloc((size_t)TOKS * 1024 * 2);
    char*  U1    =         alloc((size_t)TOKS * X12N * 2);
    bf16*  qb    = (bf16*)U1;
    bf16*  kb    = qb + (size_t)TOKS * 1024;
    bf16*  vb    = kb + (size_t)TOKS * 1024;
    bf16*  ob    = vb + (size_t)TOKS * 1024;
    bf16*  x12   = (bf16*)U1;
    bf16*  g     = (bf16*)alloc((size_t)TOKS * FFNP * 2);
    bf16*  wqkvb = (bf16*)alloc((size_t)3072 * 1024 * 2);
    bf16*  wprjb = (bf16*)alloc((size_t)1024 * 1024 * 2);
    bf16*  w12b  = (bf16*)alloc((size_t)X12N * 1024 * 2);
    bf16*  w3p   = (bf16*)alloc((size_t)1024 * FFNP * 2);
    (void)ws_size; (void)in_sizes; (void)n_in; (void)out_size;

    small_gemm<<<dim3(1024 / 4), 256, 0, stream>>>(nullptr, t_in, t_w, t_b, cs, 1024, 256, 1, 1);
    patch_embed<<<dim3(TOKS), 256, 0, stream>>>(x, patch_w, patch_b, h);

    for (int d = 0; d < 8; d++) {
        small_gemm<<<dim3(6144 / 4), 256, 0, stream>>>(cs, nullptr,
            ada_w + (size_t)d * 6144 * 1024, ada_b + (size_t)d * 6144, ada, 6144, 1024, 0, 0);
        norm_mod<<<dim3(TOKS), 256, 0, stream>>>(h, norm1_w + (size_t)d * 1024, ada, 0, 1024, 6144, hn);
        conv_bf16<<<dim3(3072 * 1024 / 4 / 256), 256, 0, stream>>>(qkv_w + (size_t)d * 3072 * 1024, wqkvb, 3072 * 1024);
        gemm128<<<dim3(3072 / 256, TOKS / 128), 512, 0, stream>>>(hn,
            wqkvb, qkv_b + (size_t)d * 3072, 1024, 3072, EPI_QKV,
            nullptr, 0, qb, kb, vb, nullptr, nullptr, 0);
        rope_qk<<<dim3(256, 128), 256, 0, stream>>>(qb, kb, qn_w + (size_t)d * 64, kn_w + (size_t)d * 64);
        attn_kernel<<<dim3(16, 128), 256, 0, stream>>>(qb, kb, vb, ob);
        conv_bf16<<<dim3(1024 * 1024 / 4 / 256), 256, 0, stream>>>(proj_w + (size_t)d * 1024 * 1024, wprjb, 1024 * 1024);
        gemm128<<<dim3(1024 / 256, TOKS / 128), 512, 0, stream>>>(ob,
            wprjb, proj_b + (size_t)d * 1024, 1024, 1024, EPI_RESID,
            nullptr, 0, nullptr, nullptr, nullptr, h, ada + 2048, 6144);
        norm_mod<<<dim3(TOKS), 256, 0, stream>>>(h, norm2_w + (size_t)d * 1024, ada, 3072, 4096, 6144, hn);
        conv_bf16<<<dim3(X12N * 1024 / 4 / 256), 256, 0, stream>>>(w12_w + (size_t)d * X12N * 1024, w12b, X12N * 1024);
        gemm256<<<dim3((X12N + 255) / 256, TOKS / 256), 512, 0, stream>>>(hn,
            w12b, w12_b + (size_t)d * X12N, 1024, X12N, EPI_BF16,
            x12, X12N, nullptr, nullptr, nullptr, nullptr, nullptr, 0);
        swiglu_kernel<<<dim3(FFNP / 256, TOKS), 256, 0, stream>>>(x12, g);
        conv_pad_w3<<<dim3(FFNP / 256, 1024), 256, 0, stream>>>(w3_w + (size_t)d * 1024 * FFN_, w3p);
        gemm128<<<dim3(1024 / 256, TOKS / 128), 512, 0, stream>>>(g,
            w3p, w3_b + (size_t)d * 1024, FFNP, 1024, EPI_RESID,
            nullptr, 0, nullptr, nullptr, nullptr, h, ada + 5120, 6144);
    }

    small_gemm<<<dim3(2048 / 4), 256, 0, stream>>>(cs, nullptr, fada_w, fada_b, fada, 2048, 1024, 0, 0);
    norm_mod<<<dim3(TOKS), 256, 0, stream>>>(h, fnorm_w, fada, 0, 1024, 2048, hn);
    final_head<<<dim3(TOKS), 256, 0, stream>>>(hn, flin_w, flin_b, (float*)d_out);
}